// Round 3
// baseline (391.818 us; speedup 1.0000x reference)
//
#include <hip/hip_runtime.h>
#include <cfloat>
#include <math.h>

#define B  32
#define T  2048
#define HD 512
#define HE 1024
#define DH 1024
#define NC 32            // chunks per batch
#define TC (T / NC)      // 64 rows per block
#define WPB 4            // waves per block
#define RPW (TC / WPB)   // 16 rows per wave
#define RU 4             // rows per unrolled iteration
#define NPART (NC * WPB) // 128 partials per batch

// ---------------------------------------------------------------------------
// Main kernel: fused hid·Wh + energies + online masked softmax + context.
// One block = (b, chunk). Waves are independent in the main loop (no barriers):
// each wave owns whole rows; lane l covers cols l*4 + j*256, j=0..3.
// ---------------------------------------------------------------------------
__global__ __launch_bounds__(256, 4) void k_main(const float* __restrict__ hidden,
                                                 const float* __restrict__ enc,
                                                 const float* __restrict__ mask,
                                                 const float* __restrict__ W,
                                                 const float* __restrict__ bvec,
                                                 float* __restrict__ pctx,
                                                 float* __restrict__ pm,
                                                 float* __restrict__ ps) {
    const int bx   = blockIdx.x;
    const int b    = bx / NC;
    const int c    = bx % NC;
    const int tid  = threadIdx.x;
    const int wave = tid >> 6, lane = tid & 63;

    // ---- fused hwh = dot(concat(hidden[0,b],hidden[1,b]), Wh) + b0 ----
    __shared__ float red[WPB];
    {
        const int i0 = tid * 4;
        const float* src = (i0 < HD) ? hidden + (size_t)b * HD + i0
                                     : hidden + (size_t)(B + b) * HD + (i0 - HD);
        float4 h4 = *reinterpret_cast<const float4*>(src);
        float4 w4 = *reinterpret_cast<const float4*>(W + i0);
        float p = h4.x * w4.x + h4.y * w4.y + h4.z * w4.z + h4.w * w4.w;
        #pragma unroll
        for (int off = 32; off; off >>= 1) p += __shfl_xor(p, off);
        if (lane == 0) red[wave] = p;
    }
    __syncthreads();
    const float hb = red[0] + red[1] + red[2] + red[3] + bvec[0];

    // per-lane We slice (matches the enc columns this lane loads)
    float4 We4[4];
    #pragma unroll
    for (int j = 0; j < 4; ++j)
        We4[j] = *reinterpret_cast<const float4*>(W + DH + lane * 4 + j * 256);

    const float* encb  = enc  + (size_t)b * T * HE;
    const float* maskb = mask + (size_t)b * T;
    const int tbase = c * TC + wave * RPW;

    float m = -FLT_MAX, s = 0.f;
    float4 ctx[4];
    #pragma unroll
    for (int j = 0; j < 4; ++j) ctx[j] = make_float4(0.f, 0.f, 0.f, 0.f);

    for (int i = 0; i < RPW; i += RU) {
        float4 v[RU][4];
        float  p[RU], mk[RU];
        #pragma unroll
        for (int r = 0; r < RU; ++r) {
            const float* row = encb + (size_t)(tbase + i + r) * HE + lane * 4;
            #pragma unroll
            for (int j = 0; j < 4; ++j)
                v[r][j] = *reinterpret_cast<const float4*>(row + j * 256);
            mk[r] = maskb[tbase + i + r];
        }
        #pragma unroll
        for (int r = 0; r < RU; ++r) {
            float acc = 0.f;
            #pragma unroll
            for (int j = 0; j < 4; ++j)
                acc += v[r][j].x * We4[j].x + v[r][j].y * We4[j].y +
                       v[r][j].z * We4[j].z + v[r][j].w * We4[j].w;
            p[r] = acc;
        }
        #pragma unroll
        for (int r = 0; r < RU; ++r) {
            #pragma unroll
            for (int off = 32; off; off >>= 1) p[r] += __shfl_xor(p[r], off);
        }
        float e[RU], gm = -FLT_MAX;
        #pragma unroll
        for (int r = 0; r < RU; ++r) {
            e[r] = (mk[r] > 0.5f) ? p[r] + hb : -FLT_MAX;
            gm = fmaxf(gm, e[r]);
        }
        const float mn    = fmaxf(m, gm);
        const float scale = __expf(m - mn);  // 0 when m stale; 1 when both -FLT_MAX
        float w[RU], wsum = 0.f;
        #pragma unroll
        for (int r = 0; r < RU; ++r) {
            w[r] = (e[r] > -0.5f * FLT_MAX) ? __expf(e[r] - mn) : 0.f;
            wsum += w[r];
        }
        s = s * scale + wsum;
        #pragma unroll
        for (int j = 0; j < 4; ++j) {
            ctx[j].x *= scale; ctx[j].y *= scale; ctx[j].z *= scale; ctx[j].w *= scale;
            #pragma unroll
            for (int r = 0; r < RU; ++r) {
                ctx[j].x += w[r] * v[r][j].x;
                ctx[j].y += w[r] * v[r][j].y;
                ctx[j].z += w[r] * v[r][j].z;
                ctx[j].w += w[r] * v[r][j].w;
            }
        }
        m = mn;
    }

    // per-wave partial (unnormalized, relative to this wave's running max m)
    const int part = bx * WPB + wave;
    float* pc = pctx + (size_t)part * HE + lane * 4;
    #pragma unroll
    for (int j = 0; j < 4; ++j)
        *reinterpret_cast<float4*>(pc + j * 256) = ctx[j];
    if (lane == 0) { pm[part] = m; ps[part] = s; }
}

// ---------------------------------------------------------------------------
// Combine per-wave partials with log-sum-exp rescale, normalize, write out.
// ---------------------------------------------------------------------------
__global__ __launch_bounds__(256) void k_combine(const float* __restrict__ pctx,
                                                 const float* __restrict__ pm,
                                                 const float* __restrict__ ps,
                                                 float* __restrict__ out) {
    const int b   = blockIdx.x;
    const int tid = threadIdx.x;
    const int p0  = b * NPART;

    float M = -FLT_MAX;
    for (int c = 0; c < NPART; ++c) M = fmaxf(M, pm[p0 + c]);
    float S = 0.f;
    for (int c = 0; c < NPART; ++c) {
        float mc = pm[p0 + c];
        float f  = (mc > -0.5f * FLT_MAX) ? __expf(mc - M) : 0.f;
        S += f * ps[p0 + c];
    }
    float4 acc = {0.f, 0.f, 0.f, 0.f};
    for (int c = 0; c < NPART; ++c) {
        float mc = pm[p0 + c];
        float f  = (mc > -0.5f * FLT_MAX) ? __expf(mc - M) : 0.f;
        float4 v = *reinterpret_cast<const float4*>(pctx + (size_t)(p0 + c) * HE + tid * 4);
        acc.x += f * v.x; acc.y += f * v.y; acc.z += f * v.z; acc.w += f * v.w;
    }
    const float inv = 1.f / S;
    float4 o = {acc.x * inv, acc.y * inv, acc.z * inv, acc.w * inv};
    *reinterpret_cast<float4*>(out + (size_t)b * HE + tid * 4) = o;
}

// ---------------------------------------------------------------------------
extern "C" void kernel_launch(void* const* d_in, const int* in_sizes, int n_in,
                              void* d_out, int out_size, void* d_ws, size_t ws_size,
                              hipStream_t stream) {
    const float* hidden = (const float*)d_in[0];
    const float* enc    = (const float*)d_in[1];
    const float* mask   = (const float*)d_in[2];
    const float* W      = (const float*)d_in[3];
    const float* bvec   = (const float*)d_in[4];
    float* out = (float*)d_out;

    char*  wsb  = (char*)d_ws;
    float* pctx = (float*)wsb;                                       // B*NPART*HE floats = 16 MB
    float* pm   = (float*)(wsb + (size_t)B * NPART * HE * sizeof(float));
    float* ps   = pm + B * NPART;

    k_main   <<<B * NC, 256, 0, stream>>>(hidden, enc, mask, W, bvec, pctx, pm, ps);
    k_combine<<<B,      256, 0, stream>>>(pctx, pm, ps, out);
}

// Round 4
// 381.382 us; speedup vs baseline: 1.0274x; 1.0274x over previous
//
#include <hip/hip_runtime.h>
#include <cfloat>
#include <math.h>

#define B  32
#define T  2048
#define HD 512
#define HE 1024
#define DH 1024
#define NC 16            // chunks per batch -> B*NC = 512 blocks = 2/CU exactly
#define TC (T / NC)      // 128 rows per block
#define WPB 4            // waves per block
#define RPW (TC / WPB)   // 32 rows per wave
#define RU 2             // rows in flight (keeps v[] liveness at 32 VGPRs)
#define NPART (NC * WPB) // 64 partials per batch

// ---------------------------------------------------------------------------
// Main kernel: fused hid·Wh + energies + online masked softmax + context.
// One block = (b, chunk); waves independent (no barriers in main loop).
// Each wave owns RPW whole rows; lane l covers cols l*4 + j*256, j=0..3.
// Per-row serial online-softmax update with deferred rescale (wave-uniform
// branch: ctx rescale only when a new running max appears).
// ---------------------------------------------------------------------------
__global__ __launch_bounds__(256, 2) void k_main(const float* __restrict__ hidden,
                                                 const float* __restrict__ enc,
                                                 const float* __restrict__ mask,
                                                 const float* __restrict__ W,
                                                 const float* __restrict__ bvec,
                                                 float* __restrict__ pctx,
                                                 float* __restrict__ pm,
                                                 float* __restrict__ ps) {
    const int bx   = blockIdx.x;
    const int b    = bx / NC;
    const int c    = bx % NC;
    const int tid  = threadIdx.x;
    const int wave = tid >> 6, lane = tid & 63;

    // ---- fused hwh = dot(concat(hidden[0,b],hidden[1,b]), Wh) + b0 ----
    __shared__ float red[WPB];
    {
        const int i0 = tid * 4;
        const float* src = (i0 < HD) ? hidden + (size_t)b * HD + i0
                                     : hidden + (size_t)(B + b) * HD + (i0 - HD);
        float4 h4 = *reinterpret_cast<const float4*>(src);
        float4 w4 = *reinterpret_cast<const float4*>(W + i0);
        float p = h4.x * w4.x + h4.y * w4.y + h4.z * w4.z + h4.w * w4.w;
        #pragma unroll
        for (int off = 32; off; off >>= 1) p += __shfl_xor(p, off);
        if (lane == 0) red[wave] = p;
    }
    __syncthreads();
    const float hb = red[0] + red[1] + red[2] + red[3] + bvec[0];

    // per-lane We slice (matches the enc columns this lane loads)
    float4 We4[4];
    #pragma unroll
    for (int j = 0; j < 4; ++j)
        We4[j] = *reinterpret_cast<const float4*>(W + DH + lane * 4 + j * 256);

    const float* encb  = enc  + (size_t)b * T * HE;
    const float* maskb = mask + (size_t)b * T;
    const int tbase = c * TC + wave * RPW;

    float m = -FLT_MAX, s = 0.f;
    float4 ctx[4];
    #pragma unroll
    for (int j = 0; j < 4; ++j) ctx[j] = make_float4(0.f, 0.f, 0.f, 0.f);

    for (int i = 0; i < RPW; i += RU) {
        float4 v[RU][4];
        float  p[RU], mk[RU];
        #pragma unroll
        for (int r = 0; r < RU; ++r) {
            const float* row = encb + (size_t)(tbase + i + r) * HE + lane * 4;
            #pragma unroll
            for (int j = 0; j < 4; ++j)
                v[r][j] = *reinterpret_cast<const float4*>(row + j * 256);
            mk[r] = maskb[tbase + i + r];
        }
        #pragma unroll
        for (int r = 0; r < RU; ++r) {
            float acc = 0.f;
            #pragma unroll
            for (int j = 0; j < 4; ++j)
                acc += v[r][j].x * We4[j].x + v[r][j].y * We4[j].y +
                       v[r][j].z * We4[j].z + v[r][j].w * We4[j].w;
            p[r] = acc;
        }
        #pragma unroll
        for (int r = 0; r < RU; ++r) {
            #pragma unroll
            for (int off = 32; off; off >>= 1) p[r] += __shfl_xor(p[r], off);
        }
        // serial per-row online update (wave-uniform branches: p[r] identical
        // on all lanes after the butterfly)
        #pragma unroll
        for (int r = 0; r < RU; ++r) {
            const float e = (mk[r] > 0.5f) ? p[r] + hb : -FLT_MAX;
            if (e > m) {
                // new running max: rescale (scale==0 when m was -FLT_MAX)
                const float scale = __expf(m - e);
                s = s * scale + 1.f;
                #pragma unroll
                for (int j = 0; j < 4; ++j) {
                    ctx[j].x = ctx[j].x * scale + v[r][j].x;
                    ctx[j].y = ctx[j].y * scale + v[r][j].y;
                    ctx[j].z = ctx[j].z * scale + v[r][j].z;
                    ctx[j].w = ctx[j].w * scale + v[r][j].w;
                }
                m = e;
            } else if (e > -0.5f * FLT_MAX) {
                const float w = __expf(e - m);
                s += w;
                #pragma unroll
                for (int j = 0; j < 4; ++j) {
                    ctx[j].x += w * v[r][j].x;
                    ctx[j].y += w * v[r][j].y;
                    ctx[j].z += w * v[r][j].z;
                    ctx[j].w += w * v[r][j].w;
                }
            }
            // else: masked row (and m still -FLT_MAX, or any masked row): skip
        }
    }

    // per-wave partial (unnormalized, relative to this wave's running max m)
    const int part = bx * WPB + wave;
    float* pc = pctx + (size_t)part * HE + lane * 4;
    #pragma unroll
    for (int j = 0; j < 4; ++j)
        *reinterpret_cast<float4*>(pc + j * 256) = ctx[j];
    if (lane == 0) { pm[part] = m; ps[part] = s; }
}

// ---------------------------------------------------------------------------
// Combine per-wave partials with log-sum-exp rescale, normalize, write out.
// ---------------------------------------------------------------------------
__global__ __launch_bounds__(256) void k_combine(const float* __restrict__ pctx,
                                                 const float* __restrict__ pm,
                                                 const float* __restrict__ ps,
                                                 float* __restrict__ out) {
    const int b   = blockIdx.x;
    const int tid = threadIdx.x;
    const int p0  = b * NPART;

    float M = -FLT_MAX;
    for (int c = 0; c < NPART; ++c) M = fmaxf(M, pm[p0 + c]);
    float S = 0.f;
    for (int c = 0; c < NPART; ++c) {
        float mc = pm[p0 + c];
        float f  = (mc > -0.5f * FLT_MAX) ? __expf(mc - M) : 0.f;
        S += f * ps[p0 + c];
    }
    float4 acc = {0.f, 0.f, 0.f, 0.f};
    for (int c = 0; c < NPART; ++c) {
        float mc = pm[p0 + c];
        float f  = (mc > -0.5f * FLT_MAX) ? __expf(mc - M) : 0.f;
        float4 v = *reinterpret_cast<const float4*>(pctx + (size_t)(p0 + c) * HE + tid * 4);
        acc.x += f * v.x; acc.y += f * v.y; acc.z += f * v.z; acc.w += f * v.w;
    }
    const float inv = 1.f / S;
    float4 o = {acc.x * inv, acc.y * inv, acc.z * inv, acc.w * inv};
    *reinterpret_cast<float4*>(out + (size_t)b * HE + tid * 4) = o;
}

// ---------------------------------------------------------------------------
extern "C" void kernel_launch(void* const* d_in, const int* in_sizes, int n_in,
                              void* d_out, int out_size, void* d_ws, size_t ws_size,
                              hipStream_t stream) {
    const float* hidden = (const float*)d_in[0];
    const float* enc    = (const float*)d_in[1];
    const float* mask   = (const float*)d_in[2];
    const float* W      = (const float*)d_in[3];
    const float* bvec   = (const float*)d_in[4];
    float* out = (float*)d_out;

    char*  wsb  = (char*)d_ws;
    float* pctx = (float*)wsb;                                       // B*NPART*HE floats = 8 MB
    float* pm   = (float*)(wsb + (size_t)B * NPART * HE * sizeof(float));
    float* ps   = pm + B * NPART;

    k_main   <<<B * NC, 256, 0, stream>>>(hidden, enc, mask, W, bvec, pctx, pm, ps);
    k_combine<<<B,      256, 0, stream>>>(pctx, pm, ps, out);
}